// Round 13
// baseline (2398.484 us; speedup 1.0000x reference)
//
#include <hip/hip_runtime.h>
#include <hip/hip_cooperative_groups.h>
#include <math.h>

namespace cg = cooperative_groups;

#define NVERT 8192
#define NEDGE 65536
#define NSUB 8
#define NCG 20
#define GRID 256
#define BLOCK 1024
#define DT 0.01f
#define KS 10000.0f
// global setup barrier grouping (R7-validated)
#define NGRP 16
#define GSIZE 16
// batch-group partitioning: 4 groups x 8 batches; 64 blocks per group.
#define NBG 4     // batch groups
#define BPGRP 8   // batches per group (= lanes per vertex)
#define GBLK 64   // blocks per group
#define VPB 128   // vertices per block
// bar lines (128 B apart): [0,16) setup grp cnts | 16 root | [17,33) releases |
// [33,65) group sg cnts (4 grp x 8 sg) | [65,69) group roots | [69,101) group rels
#define NBARLINES 101
//
// R12: shrink the sync domain. Per-batch CG solves are independent; re-partition
// so each of 4 groups (8 batches, 64 blocks, all vertices) runs its OWN 2-level
// barrier — stragglers stop multiplying across 256 blocks, barrier path shortens.
// 8 lanes x 8 B = 64 B segments keep gathers line-coalesced. Also: 4 interior
// setup grid.syncs -> global fast_bar (+sc1 setup stores; consumers first-touch
// after the barrier so L3 serves fresh). R11's LDS adjacency reverted (neutral).

struct Params {
  const float* action;   // [B][NE]
  const float* pos0;     // [B][NV][3]
  const float* vel0;     // [B][NV][3]
  const float* rest_len; // [NE]
  const float* mass;     // [NV]
  const int* edge_i;     // [NE]
  const int* edge_j;     // [NE]
  float* out;            // [B][NSUB][NV][3]
  float2* posXY;         // [NBG][NV][8] exchanged (sc1)
  float*  posZ;          // [NBG][NV][8]
  float2 *QXY0, *QXY1;   // ping-pong Ap / r0 staging (sc1)
  float  *QZ0,  *QZ1;
  float* rest_eff;       // [NBG][NE][8] read-only after setup (cached)
  int* adj_off;          // [2NE] neighbor xy byte offset (u*64), cached
  int* adjE_off;         // [2NE] edge byte offset (e*32), cached
  int* row_ptr;          // [NV+1]
  int* cursor;           // [NV]
  double* Pd;            // [2 parity][NBG][GBLK][24] block partials (sc1)
  unsigned* bar;         // [NBARLINES*32]
};

union U64F2 { unsigned long long u; float2 f; };
union U32F  { unsigned u; float f; };
union U64D  { unsigned long long u; double d; };

__device__ __forceinline__ float2 ld2_dev(const void* p) {
  U64F2 r;
  r.u = __hip_atomic_load((const unsigned long long*)p, __ATOMIC_RELAXED, __HIP_MEMORY_SCOPE_AGENT);
  return r.f;
}
__device__ __forceinline__ void st2_dev(float2* p, float2 v) {
  U64F2 r; r.f = v;
  __hip_atomic_store((unsigned long long*)p, r.u, __ATOMIC_RELAXED, __HIP_MEMORY_SCOPE_AGENT);
}
__device__ __forceinline__ float ldf_dev(const void* p) {
  U32F r;
  r.u = __hip_atomic_load((const unsigned*)p, __ATOMIC_RELAXED, __HIP_MEMORY_SCOPE_AGENT);
  return r.f;
}
__device__ __forceinline__ void stf_dev(float* p, float v) {
  U32F r; r.f = v;
  __hip_atomic_store((unsigned*)p, r.u, __ATOMIC_RELAXED, __HIP_MEMORY_SCOPE_AGENT);
}
__device__ __forceinline__ int ldi_dev(const int* p) {
  return (int)__hip_atomic_load((const unsigned*)p, __ATOMIC_RELAXED, __HIP_MEMORY_SCOPE_AGENT);
}
__device__ __forceinline__ void sti_dev(int* p, int v) {
  __hip_atomic_store((unsigned*)p, (unsigned)v, __ATOMIC_RELAXED, __HIP_MEMORY_SCOPE_AGENT);
}
__device__ __forceinline__ double lddbl_dev(const double* p) {
  U64D r;
  r.u = __hip_atomic_load((const unsigned long long*)p, __ATOMIC_RELAXED, __HIP_MEMORY_SCOPE_AGENT);
  return r.d;
}
__device__ __forceinline__ void stdbl_dev(double* p, double v) {
  U64D r; r.d = v;
  __hip_atomic_store((unsigned long long*)p, r.u, __ATOMIC_RELAXED, __HIP_MEMORY_SCOPE_AGENT);
}

// Global hierarchical fence-free barrier — setup only (R7-validated).
__device__ __forceinline__ void fast_bar(unsigned* bar, unsigned ep) {
  __syncthreads();
  if (threadIdx.x == 0) {
    const unsigned g = blockIdx.x >> 4;
    const unsigned old = __hip_atomic_fetch_add(bar + g * 32, 1u,
                          __ATOMIC_RELAXED, __HIP_MEMORY_SCOPE_AGENT);
    if (old == GSIZE * ep - 1) {
      const unsigned old2 = __hip_atomic_fetch_add(bar + NGRP * 32, 1u,
                             __ATOMIC_RELAXED, __HIP_MEMORY_SCOPE_AGENT);
      if (old2 == NGRP * ep - 1) {
#pragma unroll
        for (int i = 0; i < NGRP; ++i)
          __hip_atomic_store(bar + (NGRP + 1 + i) * 32, ep,
                             __ATOMIC_RELAXED, __HIP_MEMORY_SCOPE_AGENT);
      }
    }
    while (__hip_atomic_load(bar + (NGRP + 1 + g) * 32,
                             __ATOMIC_RELAXED, __HIP_MEMORY_SCOPE_AGENT) < ep)
      __builtin_amdgcn_s_sleep(1);
  }
  __syncthreads();
}

// Group-local 2-level fence-free barrier: 64 blocks = 8 subgroups x 8.
// Payload sc1 stores drained by the leading __syncthreads (vmcnt0 before
// s_barrier) before the arrival RMW — R6..R10-validated ordering.
__device__ __forceinline__ void group_bar(unsigned* bar, unsigned ep, int grp, int sg) {
  __syncthreads();
  if (threadIdx.x == 0) {
    unsigned* cnt  = bar + (33 + grp * 8 + sg) * 32;
    unsigned* root = bar + (65 + grp) * 32;
    unsigned* rel  = bar + (69 + grp * 8 + sg) * 32;
    const unsigned old = __hip_atomic_fetch_add(cnt, 1u,
                          __ATOMIC_RELAXED, __HIP_MEMORY_SCOPE_AGENT);
    if (old == 8 * ep - 1) {
      const unsigned old2 = __hip_atomic_fetch_add(root, 1u,
                             __ATOMIC_RELAXED, __HIP_MEMORY_SCOPE_AGENT);
      if (old2 == 8 * ep - 1) {
#pragma unroll
        for (int i = 0; i < 8; ++i)
          __hip_atomic_store(bar + (69 + grp * 8 + i) * 32, ep,
                             __ATOMIC_RELAXED, __HIP_MEMORY_SCOPE_AGENT);
      }
    }
    while (__hip_atomic_load(rel, __ATOMIC_RELAXED, __HIP_MEMORY_SCOPE_AGENT) < ep)
      __builtin_amdgcn_s_sleep(1);
  }
  __syncthreads();
}

// Publish 3 per-thread doubles (sublane c = tid&7) -> Pd[par][grp][blkg][24].
// Quantity layout: entry q*8+c, q in {rs, pAp, ApAp}. No trailing sync —
// must be followed by group_bar.
__device__ __forceinline__ void publish_store(double* Pd, int par, int grp, int blkg,
                                              double d0, double d1, double d2,
                                              double* lds_red) {
  d0 += __shfl_down(d0, 32); d0 += __shfl_down(d0, 16); d0 += __shfl_down(d0, 8);
  d1 += __shfl_down(d1, 32); d1 += __shfl_down(d1, 16); d1 += __shfl_down(d1, 8);
  d2 += __shfl_down(d2, 32); d2 += __shfl_down(d2, 16); d2 += __shfl_down(d2, 8);
  const int lane = threadIdx.x & 63, w = threadIdx.x >> 6;
  if (lane < 8) {  // lanes 0..7 hold sums over lanes == lane (mod 8)
    lds_red[w * 24 + lane] = d0;
    lds_red[w * 24 + 8 + lane] = d1;
    lds_red[w * 24 + 16 + lane] = d2;
  }
  __syncthreads();
  if (threadIdx.x < 24) {
    double s = 0.0;
#pragma unroll
    for (int ww = 0; ww < BLOCK / 64; ++ww) s += lds_red[ww * 24 + threadIdx.x];
    stdbl_dev(&Pd[((size_t)par * NBG + grp) * GBLK * 24 + (size_t)blkg * 24 + threadIdx.x], s);
  }
}

__global__ void __launch_bounds__(BLOCK) mass_spring_kernel(Params P) {
  cg::grid_group grid = cg::this_grid();
  __shared__ double lds_red[(BLOCK / 64) * 24];  // 3 KB
  __shared__ double lds_part[GBLK * 24];         // 12 KB (1536)
  __shared__ double lds_acc[24];
  __shared__ int lds_scan[BLOCK];                // 4 KB (setup only)

  const int tid = threadIdx.x;
  const int gtid = blockIdx.x * BLOCK + tid;
  const int c = tid & 7;           // batch sublane
  const int vloc = tid >> 3;       // 0..127
  const int grp = blockIdx.x >> 6; // 0..3
  const int blkg = blockIdx.x & 63;
  const int sg = blkg >> 3;
  const int v = blkg * VPB + vloc;
  const int bat = grp * BPGRP + c;
  const size_t idx = (size_t)grp * NVERT * 8 + (size_t)v * 8 + c;  // plane elem idx
  unsigned epG = 0;  // global setup epochs
  unsigned ep = 0;   // group epochs

  // ---------- setup ----------
  for (int i = gtid; i < NEDGE * 32; i += GRID * BLOCK) {
    const int e = i >> 5, b = i & 31;
    stf_dev(&P.rest_eff[((size_t)(b >> 3) * NEDGE + e) * 8 + (b & 7)],
            P.rest_len[e] * (1.0f + P.action[b * NEDGE + e]));
  }
  float3 pv, vv;
  pv.x = P.pos0[((size_t)bat * NVERT + v) * 3 + 0];
  pv.y = P.pos0[((size_t)bat * NVERT + v) * 3 + 1];
  pv.z = P.pos0[((size_t)bat * NVERT + v) * 3 + 2];
  vv.x = P.vel0[((size_t)bat * NVERT + v) * 3 + 0];
  vv.y = P.vel0[((size_t)bat * NVERT + v) * 3 + 1];
  vv.z = P.vel0[((size_t)bat * NVERT + v) * 3 + 2];
  st2_dev(&P.posXY[idx], make_float2(pv.x, pv.y));
  stf_dev(&P.posZ[idx], pv.z);
  if (gtid < NVERT) sti_dev(&P.cursor[gtid], 0);
  if (gtid < NBARLINES * 32) P.bar[gtid] = 0u;
  grid.sync();  // the ONE full-fence sync: publishes bar=0 everywhere

  if (gtid < NEDGE) {
    atomicAdd(&P.cursor[P.edge_i[gtid]], 1);
    atomicAdd(&P.cursor[P.edge_j[gtid]], 1);
  }
  fast_bar(P.bar, ++epG);

  if (blockIdx.x == 0) {  // exclusive scan of degrees, 8 per thread (sc1 I/O)
    const int base = tid * (NVERT / BLOCK);
    int loc[NVERT / BLOCK];
    int sum = 0;
#pragma unroll
    for (int i = 0; i < NVERT / BLOCK; ++i) { loc[i] = ldi_dev(&P.cursor[base + i]); sum += loc[i]; }
    lds_scan[tid] = sum;
    __syncthreads();
    for (int off = 1; off < BLOCK; off <<= 1) {
      int t = 0;
      if (tid >= off) t = lds_scan[tid - off];
      __syncthreads();
      if (tid >= off) lds_scan[tid] += t;
      __syncthreads();
    }
    int run = lds_scan[tid] - sum;
#pragma unroll
    for (int i = 0; i < NVERT / BLOCK; ++i) {
      sti_dev(&P.row_ptr[base + i], run);
      sti_dev(&P.cursor[base + i], run);
      run += loc[i];
    }
    if (tid == BLOCK - 1) sti_dev(&P.row_ptr[NVERT], run);
  }
  fast_bar(P.bar, ++epG);

  if (gtid < NEDGE) {  // adjacency: xy byte offsets (u*64), edge offs (e*32)
    const int ei = P.edge_i[gtid], ej = P.edge_j[gtid];
    const int ai = atomicAdd(&P.cursor[ei], 1);
    sti_dev(&P.adj_off[ai], ej * 64); sti_dev(&P.adjE_off[ai], gtid * 32);
    const int aj = atomicAdd(&P.cursor[ej], 1);
    sti_dev(&P.adj_off[aj], ei * 64); sti_dev(&P.adjE_off[aj], gtid * 32);
  }
  fast_bar(P.bar, ++epG);

  // first-touch of row_ptr/adj/rest_eff happens only after the barriers above:
  // sc1-written data is at L3; clean reader caches fill fresh -> plain reads OK.
  const float m_v = P.mass[v];
  const int rbeg = P.row_ptr[v], rend = P.row_ptr[v + 1];
  const float degf = (float)(rend - rbeg);

  // per-thread plane base pointers (group + sublane folded in)
  const size_t xyOff = (size_t)grp * NVERT * 64 + (size_t)c * 8;
  const size_t zOff  = (size_t)grp * NVERT * 32 + (size_t)c * 4;
  const char* posXYb = (const char*)P.posXY + xyOff;
  const char* posZb  = (const char*)P.posZ + zOff;
  const char* reb    = (const char*)P.rest_eff + (size_t)grp * NEDGE * 32 + (size_t)c * 4;

  float2* qXYrd = P.QXY0; float2* qXYwr = P.QXY1;
  float*  qZrd  = P.QZ0;  float*  qZwr  = P.QZ1;
  int pub = 0;

  for (int s = 0; s < NSUB; ++s) {
    // ---------- F: spring force; stage r0 ----------
    float fx = 0.f, fy = 0.f, fz = 0.f;
#pragma unroll 4
    for (int a = rbeg; a < rend; ++a) {
      const int off = P.adj_off[a];
      const float2 pxy = ld2_dev(posXYb + off);
      const float  puz = ldf_dev(posZb + (off >> 1));
      const float re = *(const float*)(reb + P.adjE_off[a]);
      const float dx = pv.x - pxy.x, dy = pv.y - pxy.y, dz = pv.z - puz;
      const float l = sqrtf(dx * dx + dy * dy + dz * dz);
      const float coef = -KS * (l - re) / fmaxf(l, 1e-6f);
      fx += coef * dx; fy += coef * dy; fz += coef * dz;
    }
    float3 rv;
    rv.x = m_v * vv.x + DT * fx;
    rv.y = m_v * vv.y + DT * (fy - 9.8f * m_v);
    rv.z = m_v * vv.z + DT * fz;
    st2_dev(&qXYrd[idx], make_float2(rv.x, rv.y));
    stf_dev(&qZrd[idx], rv.z);
    float3 xacc = make_float3(0.f, 0.f, 0.f);
    float3 pc = rv;
    float3 ap;
    float3 Sr, Sp;
    group_bar(P.bar, ++ep, grp, sg);

    // ---------- CG: one GROUP barrier per iteration ----------
    for (int k = 0; k < NCG; ++k) {
      const char* qXYb = (const char*)qXYrd + xyOff;
      const char* qZb  = (const char*)qZrd + zOff;
      if (k == 0) {
        float sx = 0.f, sy = 0.f, sz = 0.f;
#pragma unroll 8
        for (int a = rbeg; a < rend; ++a) {
          const int off = P.adj_off[a];
          const float2 qxy = ld2_dev(qXYb + off);
          const float  qz  = ldf_dev(qZb + (off >> 1));
          sx += qxy.x; sy += qxy.y; sz += qz;
        }
        Sr = make_float3(sx, sy, sz);
        Sp = Sr;
        ap.x = (m_v + degf) * pc.x - Sp.x;
        ap.y = (m_v + degf) * pc.y - Sp.y;
        ap.z = (m_v + degf) * pc.z - Sp.z;
      } else {
        // park the group's 1536 Pd partials (full coverage) under the gather
        const double* pbase = P.Pd + ((size_t)((pub + 1) & 1) * NBG + grp) * GBLK * 24;
        const double g0 = lddbl_dev(pbase + tid);
        double g1 = 0.0;
        if (tid < GBLK * 24 - BLOCK) g1 = lddbl_dev(pbase + BLOCK + tid);
        float sx = 0.f, sy = 0.f, sz = 0.f;
#pragma unroll 8
        for (int a = rbeg; a < rend; ++a) {
          const int off = P.adj_off[a];
          const float2 qxy = ld2_dev(qXYb + off);
          const float  qz  = ldf_dev(qZb + (off >> 1));
          sx += qxy.x; sy += qxy.y; sz += qz;
        }
        lds_part[tid] = g0;
        if (tid < GBLK * 24 - BLOCK) lds_part[BLOCK + tid] = g1;
        __syncthreads();
        if (tid < 24) {
          double ssum = 0.0;
#pragma unroll
          for (int b2 = 0; b2 < GBLK; ++b2) ssum += lds_part[b2 * 24 + tid];
          lds_acc[tid] = ssum;
        }
        __syncthreads();
        const double rsx = lds_acc[c];
        const double pq  = lds_acc[8 + c];
        const double qq  = lds_acc[16 + c];
        const float alpha = (float)(rsx / (pq + 1e-12));
        const double rs_rec = (double)alpha * (double)alpha * qq - rsx;
        const float beta = (float)(rs_rec / (rsx + 1e-12));
        xacc.x += alpha * pc.x; xacc.y += alpha * pc.y; xacc.z += alpha * pc.z;
        rv.x -= alpha * ap.x; rv.y -= alpha * ap.y; rv.z -= alpha * ap.z;
        Sr.x -= alpha * sx; Sr.y -= alpha * sy; Sr.z -= alpha * sz;
        pc.x = rv.x + beta * pc.x; pc.y = rv.y + beta * pc.y; pc.z = rv.z + beta * pc.z;
        Sp.x = Sr.x + beta * Sp.x; Sp.y = Sr.y + beta * Sp.y; Sp.z = Sr.z + beta * Sp.z;
        ap.x = (m_v + degf) * pc.x - Sp.x;
        ap.y = (m_v + degf) * pc.y - Sp.y;
        ap.z = (m_v + degf) * pc.z - Sp.z;
      }
      st2_dev(&qXYwr[idx], make_float2(ap.x, ap.y));
      stf_dev(&qZwr[idx], ap.z);
      publish_store(P.Pd, pub & 1, grp, blkg,
                    (double)(rv.x * rv.x) + (double)(rv.y * rv.y) + (double)(rv.z * rv.z),
                    (double)(pc.x * ap.x) + (double)(pc.y * ap.y) + (double)(pc.z * ap.z),
                    (double)(ap.x * ap.x) + (double)(ap.y * ap.y) + (double)(ap.z * ap.z),
                    lds_red);
      group_bar(P.bar, ++ep, grp, sg);
      ++pub;
      float2* t2 = qXYrd; qXYrd = qXYwr; qXYwr = t2;
      float*  t1 = qZrd;  qZrd  = qZwr;  qZwr  = t1;
    }

    // ---------- W: final alpha, integrate, write out ----------
    {
      const double* pbase = P.Pd + ((size_t)((pub + 1) & 1) * NBG + grp) * GBLK * 24;
      lds_part[tid] = lddbl_dev(pbase + tid);
      if (tid < GBLK * 24 - BLOCK) lds_part[BLOCK + tid] = lddbl_dev(pbase + BLOCK + tid);
      __syncthreads();
      if (tid < 24) {
        double ssum = 0.0;
#pragma unroll
        for (int b2 = 0; b2 < GBLK; ++b2) ssum += lds_part[b2 * 24 + tid];
        lds_acc[tid] = ssum;
      }
      __syncthreads();
      const double rsx = lds_acc[c];
      const double pq  = lds_acc[8 + c];
      const float alpha = (float)(rsx / (pq + 1e-12));
      xacc.x += alpha * pc.x; xacc.y += alpha * pc.y; xacc.z += alpha * pc.z;
      vv = xacc;
      pv.x += DT * vv.x; pv.y += DT * vv.y; pv.z += DT * vv.z;
      st2_dev(&P.posXY[idx], make_float2(pv.x, pv.y));
      stf_dev(&P.posZ[idx], pv.z);
      float* o = P.out + (((size_t)bat * NSUB + s) * NVERT + (size_t)v) * 3;
      o[0] = pv.x; o[1] = pv.y; o[2] = pv.z;  // plain: flushed at kernel end
      group_bar(P.bar, ++ep, grp, sg);
    }
  }
}

extern "C" void kernel_launch(void* const* d_in, const int* in_sizes, int n_in,
                              void* d_out, int out_size, void* d_ws, size_t ws_size,
                              hipStream_t stream) {
  Params P;
  P.action = (const float*)d_in[0];
  P.pos0 = (const float*)d_in[1];
  P.vel0 = (const float*)d_in[2];
  P.rest_len = (const float*)d_in[3];
  P.mass = (const float*)d_in[4];
  P.edge_i = (const int*)d_in[5];
  P.edge_j = (const int*)d_in[6];
  P.out = (float*)d_out;

  char* w = (char*)d_ws;
  auto alloc = [&](size_t bytes) {
    char* p = w;
    w += (bytes + 255) & ~(size_t)255;
    return p;
  };
  const size_t xy_bytes = (size_t)NVERT * 32 * sizeof(float2);  // 2 MB
  const size_t z_bytes  = (size_t)NVERT * 32 * sizeof(float);   // 1 MB
  P.posXY = (float2*)alloc(xy_bytes);
  P.posZ  = (float*)alloc(z_bytes);
  P.QXY0  = (float2*)alloc(xy_bytes);
  P.QXY1  = (float2*)alloc(xy_bytes);
  P.QZ0   = (float*)alloc(z_bytes);
  P.QZ1   = (float*)alloc(z_bytes);
  P.rest_eff = (float*)alloc((size_t)NEDGE * 32 * sizeof(float));
  P.adj_off  = (int*)alloc((size_t)2 * NEDGE * sizeof(int));
  P.adjE_off = (int*)alloc((size_t)2 * NEDGE * sizeof(int));
  P.row_ptr  = (int*)alloc((size_t)(NVERT + 1) * sizeof(int));
  P.cursor   = (int*)alloc((size_t)NVERT * sizeof(int));
  P.Pd       = (double*)alloc((size_t)2 * NBG * GBLK * 24 * sizeof(double));
  P.bar      = (unsigned*)alloc((size_t)NBARLINES * 32 * sizeof(unsigned));

  void* args[] = { &P };
  hipLaunchCooperativeKernel(reinterpret_cast<void*>(mass_spring_kernel),
                             dim3(GRID), dim3(BLOCK), args, 0, stream);
}

// Round 14
// 2076.145 us; speedup vs baseline: 1.1553x; 1.1553x over previous
//
#include <hip/hip_runtime.h>
#include <hip/hip_cooperative_groups.h>
#include <math.h>

namespace cg = cooperative_groups;

#define NVERT 8192
#define NEDGE 65536
#define NSUB 8
#define NCG 20
#define GRID 256
#define BLOCK 1024
#define DT 0.01f
#define KS 10000.0f
#define NGRP 16   // barrier groups
#define GSIZE 16  // blocks per group (NGRP*GSIZE == GRID)
// 256x1024: the empirically valid cooperative geometry (512x512 never launches).
//
// R13 = exact revert to R10, the empirical optimum (steady ~2015 us).
// Falsified since: R11 LDS-staged adjacency (neutral -> payload L2/L3 access
// dominates the chain, not index load); R12 4x batch-group sync-domain split
// (regressed +17%: 64B/32B gather segments waste cache lines, 4x working-set
// fragmentation; FETCH +26%).
// R10 structure: one thread per (vertex,batch); batch-innermost split planes
// (float2 xy + float z, relaxed agent atomics = sc1, fence-free); pipelined
// CG (1 barrier/iter) with neighbor-sum recurrences (gather only Ap);
// hierarchical fence-free barrier with in-shadow group reduction (Pd->Gd);
// Gd broadcast (1536 f64, full coverage) parked under the gather.

struct Params {
  const float* action;   // [B][NE]
  const float* pos0;     // [B][NV][3]
  const float* vel0;     // [B][NV][3]
  const float* rest_len; // [NE]
  const float* mass;     // [NV]
  const int* edge_i;     // [NE]
  const int* edge_j;     // [NE]
  float* out;            // [B][NSUB][NV][3]
  float2* posXY;         // [NV*32] exchanged (sc1)
  float*  posZ;          // [NV*32]
  float2 *QXY0, *QXY1;   // ping-pong Ap / r0 staging (sc1)
  float  *QZ0,  *QZ1;
  float* rest_eff;       // [NE][32]  read-only after setup (cached)
  int* adj_off;          // [2NE] neighbor xy-plane byte offset (u*256), cached
  int* adjE_off;         // [2NE] edge byte offset (e*128), cached
  int* row_ptr;          // [NV+1]
  int* cursor;           // [NV]
  double* Pd;            // [2 parity][256 block][96 q] per-block partials (sc1)
  double* Gd;            // [2 parity][NGRP group][96 q] group partials (sc1)
  unsigned* bar;         // [(2*NGRP+1)*32] uints: grp cnts | root | releases
};

union U64F2 { unsigned long long u; float2 f; };
union U32F  { unsigned u; float f; };
union U64D  { unsigned long long u; double d; };

__device__ __forceinline__ float2 ld2_dev(const float2* p) {
  U64F2 r;
  r.u = __hip_atomic_load((const unsigned long long*)p, __ATOMIC_RELAXED, __HIP_MEMORY_SCOPE_AGENT);
  return r.f;
}
__device__ __forceinline__ void st2_dev(float2* p, float2 v) {
  U64F2 r; r.f = v;
  __hip_atomic_store((unsigned long long*)p, r.u, __ATOMIC_RELAXED, __HIP_MEMORY_SCOPE_AGENT);
}
__device__ __forceinline__ float ldf_dev(const float* p) {
  U32F r;
  r.u = __hip_atomic_load((const unsigned*)p, __ATOMIC_RELAXED, __HIP_MEMORY_SCOPE_AGENT);
  return r.f;
}
__device__ __forceinline__ void stf_dev(float* p, float v) {
  U32F r; r.f = v;
  __hip_atomic_store((unsigned*)p, r.u, __ATOMIC_RELAXED, __HIP_MEMORY_SCOPE_AGENT);
}
__device__ __forceinline__ double lddbl_dev(const double* p) {
  U64D r;
  r.u = __hip_atomic_load((const unsigned long long*)p, __ATOMIC_RELAXED, __HIP_MEMORY_SCOPE_AGENT);
  return r.d;
}
__device__ __forceinline__ void stdbl_dev(double* p, double v) {
  U64D r; r.d = v;
  __hip_atomic_store((unsigned long long*)p, r.u, __ATOMIC_RELAXED, __HIP_MEMORY_SCOPE_AGENT);
}

// Plain hierarchical fence-free barrier (for F/W phases: no dots published).
__device__ __forceinline__ void fast_bar(unsigned* bar, unsigned ep) {
  __syncthreads();
  if (threadIdx.x == 0) {
    const unsigned g = blockIdx.x >> 4;
    const unsigned old = __hip_atomic_fetch_add(bar + g * 32, 1u,
                          __ATOMIC_RELAXED, __HIP_MEMORY_SCOPE_AGENT);
    if (old == GSIZE * ep - 1) {
      const unsigned old2 = __hip_atomic_fetch_add(bar + NGRP * 32, 1u,
                             __ATOMIC_RELAXED, __HIP_MEMORY_SCOPE_AGENT);
      if (old2 == NGRP * ep - 1) {
#pragma unroll
        for (int i = 0; i < NGRP; ++i)
          __hip_atomic_store(bar + (NGRP + 1 + i) * 32, ep,
                             __ATOMIC_RELAXED, __HIP_MEMORY_SCOPE_AGENT);
      }
    }
    while (__hip_atomic_load(bar + (NGRP + 1 + g) * 32,
                             __ATOMIC_RELAXED, __HIP_MEMORY_SCOPE_AGENT) < ep)
      __builtin_amdgcn_s_sleep(1);
  }
  __syncthreads();
}

// Barrier WITH in-shadow group reduction (R8-validated).
__device__ __forceinline__ void fast_bar_red(unsigned* bar, unsigned ep,
                                             const double* Pd, double* Gd, int par,
                                             int* lflag) {
  __syncthreads();  // drains this block's Pd sc1 stores; joins all waves
  const unsigned g = blockIdx.x >> 4;
  if (threadIdx.x == 0) {
    const unsigned old = __hip_atomic_fetch_add(bar + g * 32, 1u,
                          __ATOMIC_RELAXED, __HIP_MEMORY_SCOPE_AGENT);
    *lflag = (old == GSIZE * ep - 1);
  }
  __syncthreads();
  if (*lflag) {  // uniform within block: group-last arriver
    if (threadIdx.x < 96) {
      const double* base = Pd + (size_t)par * 256 * 96 + (size_t)(g * GSIZE) * 96
                           + threadIdx.x;
      double s = 0.0;
#pragma unroll
      for (int j = 0; j < GSIZE; ++j) s += lddbl_dev(base + j * 96);
      stdbl_dev(&Gd[(size_t)par * NGRP * 96 + g * 96 + threadIdx.x], s);
    }
    __syncthreads();  // drain Gd stores before root arrival
    if (threadIdx.x == 0) {
      const unsigned old2 = __hip_atomic_fetch_add(bar + NGRP * 32, 1u,
                             __ATOMIC_RELAXED, __HIP_MEMORY_SCOPE_AGENT);
      if (old2 == NGRP * ep - 1) {
#pragma unroll
        for (int i = 0; i < NGRP; ++i)
          __hip_atomic_store(bar + (NGRP + 1 + i) * 32, ep,
                             __ATOMIC_RELAXED, __HIP_MEMORY_SCOPE_AGENT);
      }
    }
  }
  if (threadIdx.x == 0) {
    while (__hip_atomic_load(bar + (NGRP + 1 + g) * 32,
                             __ATOMIC_RELAXED, __HIP_MEMORY_SCOPE_AGENT) < ep)
      __builtin_amdgcn_s_sleep(1);
  }
  __syncthreads();
}

// Publish block partial of 3 per-batch doubles -> Pd[par][blk][0..95].
// No trailing __syncthreads — MUST be followed by fast_bar_red.
__device__ __forceinline__ void publish_store(double* Pd, int par, double d0, double d1,
                                              double d2, double* lds) {
  d0 += __shfl_down(d0, 32);  // lane L += L+32: same batch, paired vertex
  d1 += __shfl_down(d1, 32);
  d2 += __shfl_down(d2, 32);
  const int lane = threadIdx.x & 63, w = threadIdx.x >> 6;
  if (lane < 32) {
    lds[w * 96 + lane] = d0;
    lds[w * 96 + 32 + lane] = d1;
    lds[w * 96 + 64 + lane] = d2;
  }
  __syncthreads();
  if (threadIdx.x < 96) {
    double s = 0.0;
#pragma unroll
    for (int ww = 0; ww < BLOCK / 64; ++ww) s += lds[ww * 96 + threadIdx.x];
    stdbl_dev(&Pd[(size_t)par * 256 * 96 + (size_t)blockIdx.x * 96 + threadIdx.x], s);
  }
}

// Consumer (W phase): read ALL 1536 Gd entries -> lds_acc[q]. Deterministic.
__device__ __forceinline__ void reduce_small(const double* Gd, int par,
                                             double* lds_part, double* lds_acc) {
  const int tid = threadIdx.x;
  const double* base = Gd + (size_t)par * NGRP * 96;
  lds_part[tid] = lddbl_dev(base + tid);                      // [0,1024)
  if (tid < NGRP * 96 - BLOCK)
    lds_part[BLOCK + tid] = lddbl_dev(base + BLOCK + tid);    // [1024,1536)
  __syncthreads();
  if (tid < 96) {
    double s = 0.0;
#pragma unroll
    for (int g = 0; g < NGRP; ++g) s += lds_part[g * 96 + tid];
    lds_acc[tid] = s;
  }
  __syncthreads();
}

__global__ void __launch_bounds__(BLOCK) mass_spring_kernel(Params P) {
  cg::grid_group grid = cg::this_grid();
  __shared__ double lds_red[(BLOCK / 64) * 96];  // 12 KB
  __shared__ double lds_part[NGRP * 96];         // 12 KB
  __shared__ double lds_acc[96];                 // 768 B
  __shared__ int lds_scan[BLOCK];                // 4 KB
  __shared__ int lds_flag;

  const int tid = threadIdx.x;
  const int gtid = blockIdx.x * BLOCK + tid;
  const int b = tid & 31;
  const int v = gtid >> 5;
  const int vb = v * 32 + b;
  const int b8 = b * 8, b4 = b * 4;
  unsigned ep = 0;

  // ---------- setup (real grid.syncs publish plain writes) ----------
  for (int i = gtid; i < NEDGE * 32; i += GRID * BLOCK) {
    const int e = i >> 5, bb = i & 31;
    P.rest_eff[e * 32 + bb] = P.rest_len[e] * (1.0f + P.action[bb * NEDGE + e]);
  }
  float3 pv, vv;
  pv.x = P.pos0[(b * NVERT + v) * 3 + 0];
  pv.y = P.pos0[(b * NVERT + v) * 3 + 1];
  pv.z = P.pos0[(b * NVERT + v) * 3 + 2];
  vv.x = P.vel0[(b * NVERT + v) * 3 + 0];
  vv.y = P.vel0[(b * NVERT + v) * 3 + 1];
  vv.z = P.vel0[(b * NVERT + v) * 3 + 2];
  st2_dev(&P.posXY[vb], make_float2(pv.x, pv.y));
  stf_dev(&P.posZ[vb], pv.z);
  if (gtid < NVERT) P.cursor[gtid] = 0;
  if (gtid < (2 * NGRP + 1) * 32) P.bar[gtid] = 0u;
  grid.sync();

  if (gtid < NEDGE) {
    atomicAdd(&P.cursor[P.edge_i[gtid]], 1);
    atomicAdd(&P.cursor[P.edge_j[gtid]], 1);
  }
  grid.sync();

  if (blockIdx.x == 0) {  // exclusive scan of degrees, 8 per thread
    const int base = tid * (NVERT / BLOCK);
    int loc[NVERT / BLOCK];
    int sum = 0;
#pragma unroll
    for (int i = 0; i < NVERT / BLOCK; ++i) { loc[i] = P.cursor[base + i]; sum += loc[i]; }
    lds_scan[tid] = sum;
    __syncthreads();
    for (int off = 1; off < BLOCK; off <<= 1) {
      int t = 0;
      if (tid >= off) t = lds_scan[tid - off];
      __syncthreads();
      if (tid >= off) lds_scan[tid] += t;
      __syncthreads();
    }
    int run = lds_scan[tid] - sum;
#pragma unroll
    for (int i = 0; i < NVERT / BLOCK; ++i) {
      P.row_ptr[base + i] = run;
      P.cursor[base + i] = run;
      run += loc[i];
    }
    if (tid == BLOCK - 1) P.row_ptr[NVERT] = run;
  }
  grid.sync();

  if (gtid < NEDGE) {  // adjacency: xy-plane byte offsets (u*256)
    const int ei = P.edge_i[gtid], ej = P.edge_j[gtid];
    const int ai = atomicAdd(&P.cursor[ei], 1);
    P.adj_off[ai] = ej * 256; P.adjE_off[ai] = gtid * 128;
    const int aj = atomicAdd(&P.cursor[ej], 1);
    P.adj_off[aj] = ei * 256; P.adjE_off[aj] = gtid * 128;
  }
  grid.sync();  // adjacency/rest_eff/row_ptr now published everywhere

  const float m_v = P.mass[v];
  const int rbeg = P.row_ptr[v], rend = P.row_ptr[v + 1];
  const float degf = (float)(rend - rbeg);

  float2* qXYrd = P.QXY0; float2* qXYwr = P.QXY1;
  float*  qZrd  = P.QZ0;  float*  qZwr  = P.QZ1;
  int pub = 0;  // publish counter; parity = pub & 1

  for (int s = 0; s < NSUB; ++s) {
    // ---------- F: spring force; stage r0 into q planes ----------
    float fx = 0.f, fy = 0.f, fz = 0.f;
#pragma unroll 4
    for (int a = rbeg; a < rend; ++a) {
      const int off = P.adj_off[a];  // u*256
      const float2 pxy = ld2_dev((const float2*)((const char*)P.posXY + off + b8));
      const float  puz = ldf_dev((const float*)((const char*)P.posZ + (off >> 1) + b4));
      const float re = *(const float*)((const char*)P.rest_eff + P.adjE_off[a] + b4);
      const float dx = pv.x - pxy.x, dy = pv.y - pxy.y, dz = pv.z - puz;
      const float l = sqrtf(dx * dx + dy * dy + dz * dz);
      const float coef = -KS * (l - re) / fmaxf(l, 1e-6f);
      fx += coef * dx; fy += coef * dy; fz += coef * dz;
    }
    float3 rv;
    rv.x = m_v * vv.x + DT * fx;
    rv.y = m_v * vv.y + DT * (fy - 9.8f * m_v);
    rv.z = m_v * vv.z + DT * fz;
    st2_dev(&qXYrd[vb], make_float2(rv.x, rv.y));
    stf_dev(&qZrd[vb], rv.z);
    float3 xacc = make_float3(0.f, 0.f, 0.f);
    float3 pc = rv;                 // p_k (registers)
    float3 ap;                      // Ap_k (registers)
    float3 Sr, Sp;                  // neighbor sums of r_k, p_k (registers)
    fast_bar(P.bar, ++ep);

    // ---------- CG: one barrier per iteration, split-plane sc1 gather -------
    for (int k = 0; k < NCG; ++k) {
      if (k == 0) {
        float sx = 0.f, sy = 0.f, sz = 0.f;  // sum r0[u]
#pragma unroll 4
        for (int a = rbeg; a < rend; ++a) {
          const int off = P.adj_off[a];
          const float2 qxy = ld2_dev((const float2*)((const char*)qXYrd + off + b8));
          const float  qz  = ldf_dev((const float*)((const char*)qZrd + (off >> 1) + b4));
          sx += qxy.x; sy += qxy.y; sz += qz;
        }
        Sr = make_float3(sx, sy, sz);
        Sp = Sr;  // p0 = r0
        ap.x = (m_v + degf) * pc.x - Sp.x;
        ap.y = (m_v + degf) * pc.y - Sp.y;
        ap.z = (m_v + degf) * pc.z - Sp.z;
      } else {
        // pipeline: issue FULL-COVERAGE Gd broadcast loads first (1536 entries
        // over 1024 threads: tid and, for tid<512, 1024+tid), park in regs
        const double* gbase = P.Gd + (size_t)((pub + 1) & 1) * NGRP * 96;
        const double gval0 = lddbl_dev(gbase + tid);
        double gval1 = 0.0;
        if (tid < NGRP * 96 - BLOCK) gval1 = lddbl_dev(gbase + BLOCK + tid);
        // gather S_q = sum Ap_{k-1}[u] (hides the Gd latency)
        float sx = 0.f, sy = 0.f, sz = 0.f;
#pragma unroll 4
        for (int a = rbeg; a < rend; ++a) {
          const int off = P.adj_off[a];
          const float2 qxy = ld2_dev((const float2*)((const char*)qXYrd + off + b8));
          const float  qz  = ldf_dev((const float*)((const char*)qZrd + (off >> 1) + b4));
          sx += qxy.x; sy += qxy.y; sz += qz;
        }
        // finish the broadcast reduce in LDS (full 1536 coverage)
        lds_part[tid] = gval0;
        if (tid < NGRP * 96 - BLOCK) lds_part[BLOCK + tid] = gval1;
        __syncthreads();
        if (tid < 96) {
          double s = 0.0;
#pragma unroll
          for (int g = 0; g < NGRP; ++g) s += lds_part[g * 96 + tid];
          lds_acc[tid] = s;
        }
        __syncthreads();
        const double rsx = lds_acc[b];        // |r_{k-1}|^2 (exact)
        const double pq  = lds_acc[32 + b];   // p.Ap
        const double qq  = lds_acc[64 + b];   // Ap.Ap
        const float alpha = (float)(rsx / (pq + 1e-12));
        const double rs_rec = (double)alpha * (double)alpha * qq - rsx;
        const float beta = (float)(rs_rec / (rsx + 1e-12));
        xacc.x += alpha * pc.x; xacc.y += alpha * pc.y; xacc.z += alpha * pc.z;
        rv.x -= alpha * ap.x; rv.y -= alpha * ap.y; rv.z -= alpha * ap.z;
        Sr.x -= alpha * sx; Sr.y -= alpha * sy; Sr.z -= alpha * sz;
        pc.x = rv.x + beta * pc.x; pc.y = rv.y + beta * pc.y; pc.z = rv.z + beta * pc.z;
        Sp.x = Sr.x + beta * Sp.x; Sp.y = Sr.y + beta * Sp.y; Sp.z = Sr.z + beta * Sp.z;
        ap.x = (m_v + degf) * pc.x - Sp.x;
        ap.y = (m_v + degf) * pc.y - Sp.y;
        ap.z = (m_v + degf) * pc.z - Sp.z;
      }
      st2_dev(&qXYwr[vb], make_float2(ap.x, ap.y));
      stf_dev(&qZwr[vb], ap.z);
      publish_store(P.Pd, pub & 1,
                    (double)(rv.x * rv.x) + (double)(rv.y * rv.y) + (double)(rv.z * rv.z),
                    (double)(pc.x * ap.x) + (double)(pc.y * ap.y) + (double)(pc.z * ap.z),
                    (double)(ap.x * ap.x) + (double)(ap.y * ap.y) + (double)(ap.z * ap.z),
                    lds_red);
      fast_bar_red(P.bar, ++ep, P.Pd, P.Gd, pub & 1, &lds_flag);
      ++pub;
      float2* t2 = qXYrd; qXYrd = qXYwr; qXYwr = t2;
      float*  t1 = qZrd;  qZrd  = qZwr;  qZwr  = t1;
    }

    // ---------- W: final alpha, integrate, write out ----------
    {
      reduce_small(P.Gd, (pub + 1) & 1, lds_part, lds_acc);
      const double rsx = lds_acc[b];
      const double pq  = lds_acc[32 + b];
      const float alpha = (float)(rsx / (pq + 1e-12));
      xacc.x += alpha * pc.x; xacc.y += alpha * pc.y; xacc.z += alpha * pc.z;
      vv = xacc;
      pv.x += DT * vv.x; pv.y += DT * vv.y; pv.z += DT * vv.z;
      st2_dev(&P.posXY[vb], make_float2(pv.x, pv.y));
      stf_dev(&P.posZ[vb], pv.z);
      float* o = P.out + ((size_t)(b * NSUB + s) * NVERT + (size_t)v) * 3;
      o[0] = pv.x; o[1] = pv.y; o[2] = pv.z;  // plain: flushed at kernel end
      fast_bar(P.bar, ++ep);
    }
  }
}

extern "C" void kernel_launch(void* const* d_in, const int* in_sizes, int n_in,
                              void* d_out, int out_size, void* d_ws, size_t ws_size,
                              hipStream_t stream) {
  Params P;
  P.action = (const float*)d_in[0];
  P.pos0 = (const float*)d_in[1];
  P.vel0 = (const float*)d_in[2];
  P.rest_len = (const float*)d_in[3];
  P.mass = (const float*)d_in[4];
  P.edge_i = (const int*)d_in[5];
  P.edge_j = (const int*)d_in[6];
  P.out = (float*)d_out;

  char* w = (char*)d_ws;
  auto alloc = [&](size_t bytes) {
    char* p = w;
    w += (bytes + 255) & ~(size_t)255;
    return p;
  };
  const size_t xy_bytes = (size_t)NVERT * 32 * sizeof(float2);  // 2 MB
  const size_t z_bytes  = (size_t)NVERT * 32 * sizeof(float);   // 1 MB
  P.posXY = (float2*)alloc(xy_bytes);
  P.posZ  = (float*)alloc(z_bytes);
  P.QXY0  = (float2*)alloc(xy_bytes);
  P.QXY1  = (float2*)alloc(xy_bytes);
  P.QZ0   = (float*)alloc(z_bytes);
  P.QZ1   = (float*)alloc(z_bytes);
  P.rest_eff = (float*)alloc((size_t)NEDGE * 32 * sizeof(float));
  P.adj_off  = (int*)alloc((size_t)2 * NEDGE * sizeof(int));
  P.adjE_off = (int*)alloc((size_t)2 * NEDGE * sizeof(int));
  P.row_ptr  = (int*)alloc((size_t)(NVERT + 1) * sizeof(int));
  P.cursor   = (int*)alloc((size_t)NVERT * sizeof(int));
  P.Pd       = (double*)alloc((size_t)2 * 256 * 96 * sizeof(double));
  P.Gd       = (double*)alloc((size_t)2 * NGRP * 96 * sizeof(double));
  P.bar      = (unsigned*)alloc((size_t)(2 * NGRP + 1) * 32 * sizeof(unsigned));

  void* args[] = { &P };
  hipLaunchCooperativeKernel(reinterpret_cast<void*>(mass_spring_kernel),
                             dim3(GRID), dim3(BLOCK), args, 0, stream);
}